// Round 2
// baseline (267.099 us; speedup 1.0000x reference)
//
#include <hip/hip_runtime.h>
#include <hip/hip_bf16.h>

// Problem constants (fixed by reference setup_inputs)
#define M 4096
#define N 8192
#define D 128

typedef __attribute__((ext_vector_type(8))) short short8_t;   // 8 bf16 (MFMA A/B frag, 4 VGPRs)
typedef __attribute__((ext_vector_type(16))) float f32x16;    // 32x32 MFMA C/D frag

__device__ inline unsigned short f2bf(float f) {
    union { float f; unsigned u; } v; v.f = f;
    unsigned r = v.u + 0x7FFFu + ((v.u >> 16) & 1u);
    return (unsigned short)(r >> 16);
}

// ws layout (floats):  sxn[M] | axn[N] | sxb_t (M*64 dwords) | axb_t (N*64 dwords)
// sxb_t/axb_t: bf16 x in k-major 16-B chunks: chunk (k8, row) = x[row][8*k8 .. 8*k8+7].

// Kernel 0: row norms -> sxn/axn; bf16 k-major transposed copies -> sxb_t/axb_t; zero out.
__global__ __launch_bounds__(256) void prep_kernel(const float* __restrict__ sub_x,
                                                   const float* __restrict__ all_x,
                                                   float* __restrict__ ws,
                                                   float* __restrict__ out) {
    const int wave = threadIdx.x >> 6;
    const int lane = threadIdx.x & 63;
    const int row  = blockIdx.x * 4 + wave;   // 12288 rows = 3072 blocks * 4 waves

    unsigned* sxb = (unsigned*)(ws + M + N);
    unsigned* axb = sxb + (size_t)M * 64;

    const float* src; float* ndst; unsigned* tdst; int r, R;
    if (row < M) { r = row;     src = sub_x + (size_t)r * D; ndst = ws + r;     tdst = sxb; R = M; }
    else         { r = row - M; src = all_x + (size_t)r * D; ndst = ws + M + r; tdst = axb; R = N; }

    const float2 v = ((const float2*)src)[lane];   // elems 2*lane, 2*lane+1

    float s = v.x * v.x + v.y * v.y;
    #pragma unroll
    for (int off = 32; off > 0; off >>= 1) s += __shfl_down(s, off, 64);
    if (lane == 0) ndst[0] = s;

    const unsigned p = ((unsigned)f2bf(v.y) << 16) | (unsigned)f2bf(v.x);
    const int k8 = lane >> 2, q = lane & 3;
    tdst[((size_t)k8 * R + r) * 4 + q] = p;

    if (blockIdx.x == 0 && threadIdx.x == 0) out[0] = 0.0f;
}

// Kernel 1: block = 128x128 tile of G; wave w owns rows [w*32, w*32+32).
// 32x32x16 bf16 MFMA: C/D col = lane&31, row = (r&3)+8*(r>>2)+4*(lane>>5)  [verified, absmax 0]
//
// R8: fix the vmcnt-FIFO pipeline. Per iteration issue order is now
//   [b(jt) 8 loads] -> [gv(jt+1) 16 loads] -> sched_barrier(0) -> MFMA -> epilogue.
// vmcnt is in-order: waiting for b(jt) is vmcnt(16), which leaves the 16 gv(jt+1)
// HBM loads in flight across the MFMA chain + epilogue + next iteration's b-issue
// (full-iteration latency cover, ~4 KB/wave outstanding continuously). The
// sched_barrier(0) pins the issue point so hipcc cannot sink the prefetch batch
// down to its use (the suspected cause of R6/R7 both stalling at ~55% of BW).
__global__ __launch_bounds__(256, 3) void graph_loss_kernel(const float* __restrict__ G,
                                                            const float* __restrict__ ws,
                                                            float* __restrict__ out) {
    __shared__ float red[4];

    const int tid  = threadIdx.x;
    const int lane = tid & 63;
    const int w    = tid >> 6;
    const int c    = lane & 31;   // col within 32-tile
    const int hw   = lane >> 5;   // half-wave -> k-offset / +4 rows

    const int ti = blockIdx.x >> 6;   // 0..31
    const int tj = blockIdx.x & 63;   // 0..63
    const int i0 = ti * 128;
    const int j0 = tj * 128;

    const float* sxn = ws;
    const float* axn = ws + M;
    const uint4* sxb = (const uint4*)(ws + M + N);        // [k8*M + m]
    const uint4* axb = sxb + (size_t)16 * M;              // [k8*N + j]

    const float* gbase = G + (size_t)(i0 + w * 32 + 4 * hw) * N + j0 + c;

    // ---- Issue jt=0 G loads FIRST (HBM, longest latency), pin them early ----
    float gv[2][16];
    #pragma unroll
    for (int r = 0; r < 16; ++r)
        gv[0][r] = gbase[(size_t)((r & 3) + 8 * (r >> 2)) * N];
    __builtin_amdgcn_sched_barrier(0);

    // ---- A fragments: 8 k-steps, 16-B chunks, half-wave-coalesced (L2) ----
    short8_t a_frag[8];
    #pragma unroll
    for (int kk = 0; kk < 8; ++kk) {
        const uint4 t = sxb[(size_t)(kk * 2 + hw) * M + i0 + w * 32 + c];
        a_frag[kk] = *(const short8_t*)&t;
    }

    // ---- per-row norms for this wave's 32 rows (C-layout order) ----
    float sxv[16];
    #pragma unroll
    for (int r = 0; r < 16; ++r)
        sxv[r] = sxn[i0 + w * 32 + (r & 3) + 8 * (r >> 2) + 4 * hw];

    float axv[4];
    #pragma unroll
    for (int jt = 0; jt < 4; ++jt)
        axv[jt] = axn[j0 + jt * 32 + c];

    // B fragment base: axb[(kk*2+hw)*N + j0 + jt*32 + c]
    const uint4* bbase = axb + (size_t)hw * N + j0 + c;

    float local = 0.0f;

    #pragma unroll
    for (int jt = 0; jt < 4; ++jt) {
        // (1) this jt's 8 B fragments (L2 hits) — issued BEFORE the gv prefetch so
        //     the MFMA wait is vmcnt(16), not vmcnt(0).
        short8_t b[8];
        #pragma unroll
        for (int kk = 0; kk < 8; ++kk) {
            const uint4 t = bbase[(size_t)(kk * 2) * N + jt * 32];
            b[kk] = *(const short8_t*)&t;
        }

        // (2) next jt's G tile-slice (HBM) — stays in flight through MFMA + epilogue
        if (jt < 3) {
            #pragma unroll
            for (int r = 0; r < 16; ++r)
                gv[(jt + 1) & 1][r] = gbase[(size_t)((r & 3) + 8 * (r >> 2)) * N + (jt + 1) * 32];
        }

        // (3) pin the issue point: hipcc may not sink the loads below this
        __builtin_amdgcn_sched_barrier(0);

        f32x16 acc;
        #pragma unroll
        for (int r = 0; r < 16; ++r) acc[r] = 0.0f;

        #pragma unroll
        for (int kk = 0; kk < 8; ++kk)
            acc = __builtin_amdgcn_mfma_f32_32x32x16_bf16(a_frag[kk], b[kk], acc, 0, 0, 0);

        const float av = axv[jt];
        #pragma unroll
        for (int r = 0; r < 16; ++r)
            local += gv[jt & 1][r] * (sxv[r] + av - 2.0f * acc[r]);
    }

    // ---- Reduce: wave shuffle -> LDS -> one atomic per block (pre-scaled; /2^25 exact) ----
    #pragma unroll
    for (int off = 32; off > 0; off >>= 1) local += __shfl_down(local, off, 64);
    if (lane == 0) red[w] = local;
    __syncthreads();
    if (tid == 0) {
        const float bsum = red[0] + red[1] + red[2] + red[3];
        atomicAdd(out, bsum * (1.0f / 33554432.0f));   // / (m*n) = / 2^25
    }
}

extern "C" void kernel_launch(void* const* d_in, const int* in_sizes, int n_in,
                              void* d_out, int out_size, void* d_ws, size_t ws_size,
                              hipStream_t stream) {
    const float* G      = (const float*)d_in[0];  // [M,N]
    const float* sub_x  = (const float*)d_in[1];  // [M,D]
    const float* all_x  = (const float*)d_in[2];  // [N,D]
    float* out = (float*)d_out;
    float* ws  = (float*)d_ws;                    // ~3.1 MB used

    prep_kernel<<<(M + N) / 4, 256, 0, stream>>>(sub_x, all_x, ws, out);
    graph_loss_kernel<<<(M / 128) * (N / 128), 256, 0, stream>>>(G, ws, out);
}

// Round 3
// 199.160 us; speedup vs baseline: 1.3411x; 1.3411x over previous
//
#include <hip/hip_runtime.h>
#include <hip/hip_bf16.h>

// Problem constants (fixed by reference setup_inputs)
#define M 4096
#define N 8192
#define D 128

// Tile geometry: block = 32 G-rows x 1024 G-cols, processed in 8 chunks of 128 cols.
#define I_T 32
#define J_T 1024
#define JC  128
#define NC  (J_T / JC)   // 8

typedef __attribute__((ext_vector_type(8))) short short8_t;   // 8 bf16 (MFMA A/B frag)
typedef __attribute__((ext_vector_type(16))) float f32x16;    // 32x32 MFMA C/D frag

__device__ inline unsigned short f2bf(float f) {
    union { float f; unsigned u; } v; v.f = f;
    unsigned r = v.u + 0x7FFFu + ((v.u >> 16) & 1u);
    return (unsigned short)(r >> 16);
}

// ws layout (floats):  sxn[M] | axn[N] | sxb_t (M*64 dwords) | axb_t (N*64 dwords)
__global__ __launch_bounds__(256) void prep_kernel(const float* __restrict__ sub_x,
                                                   const float* __restrict__ all_x,
                                                   float* __restrict__ ws,
                                                   float* __restrict__ out) {
    const int wave = threadIdx.x >> 6;
    const int lane = threadIdx.x & 63;
    const int row  = blockIdx.x * 4 + wave;

    unsigned* sxb = (unsigned*)(ws + M + N);
    unsigned* axb = sxb + (size_t)M * 64;

    const float* src; float* ndst; unsigned* tdst; int r, R;
    if (row < M) { r = row;     src = sub_x + (size_t)r * D; ndst = ws + r;     tdst = sxb; R = M; }
    else         { r = row - M; src = all_x + (size_t)r * D; ndst = ws + M + r; tdst = axb; R = N; }

    const float2 v = ((const float2*)src)[lane];

    float s = v.x * v.x + v.y * v.y;
    #pragma unroll
    for (int off = 32; off > 0; off >>= 1) s += __shfl_down(s, off, 64);
    if (lane == 0) ndst[0] = s;

    const unsigned p = ((unsigned)f2bf(v.y) << 16) | (unsigned)f2bf(v.x);
    const int k8 = lane >> 2, q = lane & 3;
    tdst[((size_t)k8 * R + r) * 4 + q] = p;

    if (blockIdx.x == 0 && threadIdx.x == 0) out[0] = 0.0f;
}

// R9: contiguous-G streaming. Per chunk: MFMA P(32x128) -> w into LDS (MFMA-native
// layout [jsub][r][hw][c], conflict-free writes) -> G streamed as float4 (512 B
// sequential runs per row) with dense ds_read_b128 of w. Raw s_barrier (+lgkmcnt(0))
// so in-flight G prefetch (issued 2 chunks ahead) is NOT drained at phase ends.
// b-fragments issue BEFORE G in each phase so the MFMA vmcnt wait keeps G in flight.
//
// PHASE(T): [b(T+1) loads] [GFMA(T): read w from wls[PB], fma with GC] [issue G(T+2)
// into GC] [MFMA(T+1) + write w(T+1) -> wls[QB]; lgkmcnt(0); s_barrier]
#define PHASE(T, GC, PBASE, QBASE)                                                     \
  {                                                                                    \
    if ((T) + 1 < NC) {                                                                \
      _Pragma("unroll")                                                                \
      for (int kk = 0; kk < 8; ++kk) {                                                 \
        const uint4 tb = axb[(size_t)(kk * 2 + hw) * N + j0 + ((T) + 1) * JC + w * 32 + c]; \
        b[kk] = *(const short8_t*)&tb;                                                 \
      }                                                                                \
    }                                                                                  \
    _Pragma("unroll")                                                                  \
    for (int s = 0; s < 4; ++s) {                                                      \
      const int rh = 2 * s + hw;                                                       \
      const int waddr = (PBASE) + (c >> 3) * 1024 + ((rh & 3) + 4 * w) * 64            \
                        + ((rh >> 2) & 1) * 32 + 4 * (c & 7);                          \
      const float4 wv = *(const float4*)&wls[waddr];                                   \
      local += GC[s].x * wv.x + GC[s].y * wv.y + GC[s].z * wv.z + GC[s].w * wv.w;      \
    }                                                                                  \
    if ((T) + 2 < NC) {                                                                \
      _Pragma("unroll")                                                                \
      for (int s = 0; s < 4; ++s)                                                      \
        GC[s] = *(const float4*)(gl + (size_t)(2 * s) * N + ((T) + 2) * JC);           \
    }                                                                                  \
    if ((T) + 1 < NC) {                                                                \
      _Pragma("unroll")                                                                \
      for (int r = 0; r < 16; ++r) acc[r] = 0.0f;                                      \
      _Pragma("unroll")                                                                \
      for (int kk = 0; kk < 8; ++kk)                                                   \
        acc = __builtin_amdgcn_mfma_f32_32x32x16_bf16(a_frag[kk], b[kk], acc, 0, 0, 0);\
      const float axv = axn[j0 + ((T) + 1) * JC + w * 32 + c];                         \
      _Pragma("unroll")                                                                \
      for (int r = 0; r < 16; ++r)                                                     \
        wls[(QBASE) + w * 1024 + r * 64 + hw * 32 + c] = sxv[r] + axv - 2.0f * acc[r]; \
      asm volatile("s_waitcnt lgkmcnt(0)" ::: "memory");                               \
      __builtin_amdgcn_s_barrier();                                                    \
    }                                                                                  \
  }

__global__ __launch_bounds__(256, 3) void graph_loss_kernel(const float* __restrict__ G,
                                                            const float* __restrict__ ws,
                                                            float* __restrict__ out) {
    __shared__ float wls[2 * 4096];   // [par][jsub:4][r:16][hw:2][c:32] f32, 32 KB
    __shared__ float red[4];

    const int tid  = threadIdx.x;
    const int lane = tid & 63;
    const int w    = tid >> 6;
    const int c    = lane & 31;
    const int hw   = lane >> 5;

    // bid = ti*8 + tj: tj = bid%8 == XCD id -> each XCD caches exactly one 256 KB axb slice.
    const int ti = blockIdx.x >> 3;    // 0..127
    const int tj = blockIdx.x & 7;     // 0..7
    const int i0 = ti * I_T;
    const int j0 = tj * J_T;

    const float* sxn = ws;
    const float* axn = ws + M;
    const uint4* sxb = (const uint4*)(ws + M + N);
    const uint4* axb = sxb + (size_t)16 * M;

    // Persistent A fragments + row norms (all 4 waves share the same 32 i-rows)
    short8_t a_frag[8];
    #pragma unroll
    for (int kk = 0; kk < 8; ++kk) {
        const uint4 t = sxb[(size_t)(kk * 2 + hw) * M + i0 + c];
        a_frag[kk] = *(const short8_t*)&t;
    }
    float sxv[16];
    #pragma unroll
    for (int r = 0; r < 16; ++r)
        sxv[r] = sxn[i0 + (r & 3) + 8 * (r >> 2) + 4 * hw];

    // G lane base: lane reads rows i0 + w*8 + 2s + hw, cols j0 + t*JC + 4c .. +3
    const float* gl = G + (size_t)(i0 + w * 8 + hw) * N + j0 + 4 * c;

    float  local = 0.0f;
    float4 gA[4], gB[4];
    f32x16 acc;
    short8_t b[8];

    // ---- Prologue: chunk 0 (b first, then G(0), so MFMA's vmcnt wait keeps G in flight) ----
    #pragma unroll
    for (int kk = 0; kk < 8; ++kk) {
        const uint4 tb = axb[(size_t)(kk * 2 + hw) * N + j0 + w * 32 + c];
        b[kk] = *(const short8_t*)&tb;
    }
    #pragma unroll
    for (int s = 0; s < 4; ++s)
        gA[s] = *(const float4*)(gl + (size_t)(2 * s) * N);

    #pragma unroll
    for (int r = 0; r < 16; ++r) acc[r] = 0.0f;
    #pragma unroll
    for (int kk = 0; kk < 8; ++kk)
        acc = __builtin_amdgcn_mfma_f32_32x32x16_bf16(a_frag[kk], b[kk], acc, 0, 0, 0);

    #pragma unroll
    for (int s = 0; s < 4; ++s)
        gB[s] = *(const float4*)(gl + (size_t)(2 * s) * N + JC);   // G(1)

    {
        const float axv = axn[j0 + w * 32 + c];
        #pragma unroll
        for (int r = 0; r < 16; ++r)
            wls[w * 1024 + r * 64 + hw * 32 + c] = sxv[r] + axv - 2.0f * acc[r];
    }
    asm volatile("s_waitcnt lgkmcnt(0)" ::: "memory");
    __builtin_amdgcn_s_barrier();

    // ---- 8 phases, statically expanded (no runtime-indexed register arrays) ----
    PHASE(0, gA, 0, 4096)
    PHASE(1, gB, 4096, 0)
    PHASE(2, gA, 0, 4096)
    PHASE(3, gB, 4096, 0)
    PHASE(4, gA, 0, 4096)
    PHASE(5, gB, 4096, 0)
    PHASE(6, gA, 0, 4096)
    PHASE(7, gB, 4096, 0)

    // ---- Reduce: wave shuffle -> LDS -> one atomic per block (pre-scaled; /2^25 exact) ----
    #pragma unroll
    for (int off = 32; off > 0; off >>= 1) local += __shfl_down(local, off, 64);
    if (lane == 0) red[w] = local;
    __syncthreads();
    if (tid == 0) {
        const float bsum = red[0] + red[1] + red[2] + red[3];
        atomicAdd(out, bsum * (1.0f / 33554432.0f));   // / (m*n) = / 2^25
    }
}

extern "C" void kernel_launch(void* const* d_in, const int* in_sizes, int n_in,
                              void* d_out, int out_size, void* d_ws, size_t ws_size,
                              hipStream_t stream) {
    const float* G      = (const float*)d_in[0];  // [M,N]
    const float* sub_x  = (const float*)d_in[1];  // [M,D]
    const float* all_x  = (const float*)d_in[2];  // [N,D]
    float* out = (float*)d_out;
    float* ws  = (float*)d_ws;

    prep_kernel<<<(M + N) / 4, 256, 0, stream>>>(sub_x, all_x, ws, out);
    graph_loss_kernel<<<(M / I_T) * (N / J_T), 256, 0, stream>>>(G, ws, out);
}